// Round 12
// baseline (235.717 us; speedup 1.0000x reference)
//
#include <hip/hip_runtime.h>
#include <hip/hip_bf16.h>

// Sizes (fixed by the reference)
#define BI 64
#define BC 64
#define TCAP 64
#define D 1024
#define H 128
#define TIMG 36

// ---------------- Kernel A: img stats | cap partial stats | W1 transpose | cnt zero ----------------
// grid 193 x 1024:  blk<64: img   64<=blk<128: capstat   128<=blk<192: w1t   blk==192: zero counters
__global__ __launch_bounds__(1024) void k_pre(const float* __restrict__ img,
                                              const float* __restrict__ cap,
                                              const float* __restrict__ Wg1,
                                              const float* __restrict__ Wb1,
                                              float* __restrict__ repr,
                                              float* __restrict__ ivec,
                                              float* __restrict__ part,
                                              float* __restrict__ W1T,
                                              int* __restrict__ cnt) {
    int blk = blockIdx.x, tid = threadIdx.x;
    int tg = tid >> 8, dq = tid & 255;      // t-group, float4 channel slot
    __shared__ float4 redA[1024];
    __shared__ float4 redB[1024];
    if (blk == 192) {
        if (tid < 64) cnt[tid] = 0;
        return;
    }
    if (blk < 64) {
        // ---- img_repr mean + l2-normalized img_vec ----
        int i = blk;
        const float4* base = (const float4*)(img + (size_t)i * TIMG * D);
        float4 s = {0.f, 0.f, 0.f, 0.f};
#pragma unroll
        for (int t = 0; t < 9; ++t) {
            float4 v = base[(tg * 9 + t) * 256 + dq];
            s.x += v.x; s.y += v.y; s.z += v.z; s.w += v.w;
        }
        redA[tg * 256 + dq] = s;
        __syncthreads();
        float4 m;
        if (tg == 0) {
            float4 a = redA[dq], b = redA[256 + dq], c = redA[512 + dq], d = redA[768 + dq];
            m.x = (a.x + b.x + c.x + d.x) * (1.f / 36.f);
            m.y = (a.y + b.y + c.y + d.y) * (1.f / 36.f);
            m.z = (a.z + b.z + c.z + d.z) * (1.f / 36.f);
            m.w = (a.w + b.w + c.w + d.w) * (1.f / 36.f);
            ((float4*)(repr + (size_t)i * D))[dq] = m;
            float loc = m.x * m.x + m.y * m.y + m.z * m.z + m.w * m.w;
            for (int off = 32; off; off >>= 1) loc += __shfl_xor(loc, off);
            if ((tid & 63) == 0) redB[dq >> 6].x = loc;   // waves 0..3 of tg0
        }
        __syncthreads();
        if (tg == 0) {
            float inv = rsqrtf(redB[0].x + redB[1].x + redB[2].x + redB[3].x);
            float4 o = {m.x * inv, m.y * inv, m.z * inv, m.w * inv};
            ((float4*)(ivec + (size_t)i * D))[dq] = o;
        }
    } else if (blk < 128) {
        // ---- per-channel sums over t<36 for one caption b ----
        int b = blk - 64;
        const float4* base = (const float4*)(cap + (size_t)b * TCAP * D);
        float4 s = {0.f, 0.f, 0.f, 0.f}, ss = {0.f, 0.f, 0.f, 0.f};
#pragma unroll
        for (int t = 0; t < 9; ++t) {
            float4 v = base[(tg * 9 + t) * 256 + dq];
            s.x += v.x; s.y += v.y; s.z += v.z; s.w += v.w;
            ss.x = fmaf(v.x, v.x, ss.x); ss.y = fmaf(v.y, v.y, ss.y);
            ss.z = fmaf(v.z, v.z, ss.z); ss.w = fmaf(v.w, v.w, ss.w);
        }
        redA[tg * 256 + dq] = s;
        redB[tg * 256 + dq] = ss;
        __syncthreads();
        if (tg == 0) {
            float4 a = redA[dq], b1 = redA[256 + dq], c = redA[512 + dq], d = redA[768 + dq];
            float4 S = {a.x + b1.x + c.x + d.x, a.y + b1.y + c.y + d.y,
                        a.z + b1.z + c.z + d.z, a.w + b1.w + c.w + d.w};
            float4 e = redB[dq], f = redB[256 + dq], g = redB[512 + dq], h = redB[768 + dq];
            float4 SS = {e.x + f.x + g.x + h.x, e.y + f.y + g.y + h.y,
                         e.z + f.z + g.z + h.z, e.w + f.w + g.w + h.w};
            ((float4*)(part + b * 2048))[dq] = S;
            ((float4*)(part + b * 2048 + 1024))[dq] = SS;
        }
    } else {
        // ---- transpose+concat W1 -> W1T[256][1024] (16 waves: 4 rows each pass) ----
        __shared__ float tile[64][65];
        int idx = blk - 128;
        int bx = idx & 15, by = (idx >> 4) & 1, bz = idx >> 5;
        const float* W = bz ? Wb1 : Wg1;
        int d0 = bx * 64, c0 = by * 64;
        int lane = tid & 63, w = tid >> 6;   // w in [0,16)
#pragma unroll
        for (int k = 0; k < 4; ++k) {
            int dl = k * 16 + w;
            tile[dl][lane] = W[(size_t)(d0 + dl) * H + c0 + lane];
        }
        __syncthreads();
#pragma unroll
        for (int k = 0; k < 4; ++k) {
            int cl = k * 16 + w;
            W1T[(size_t)(bz * 128 + c0 + cl) * D + d0 + lane] = tile[lane][cl];
        }
    }
}

// ---------------- Kernel B: stat finalize | hidden layer + last-block layer-2 epilogue ----------------
// grid 4164 x 256: blk<4: mu/istd   4<=blk<68: unused-lite (kept small)   else: hidden + epilogue
// Hidden: one wave per (i,c); 64 blocks per image. 64th finisher computes gam/bet for image i.
__global__ __launch_bounds__(256) void k_mid(const float* __restrict__ part,
                                             const float* __restrict__ repr,
                                             const float* __restrict__ W1T,
                                             const float* __restrict__ bg1,
                                             const float* __restrict__ bb1,
                                             const float* __restrict__ Wg2, const float* __restrict__ bg2,
                                             const float* __restrict__ Wb2, const float* __restrict__ bb2,
                                             float* __restrict__ mu,
                                             float* __restrict__ istd,
                                             float* __restrict__ hid,
                                             int* __restrict__ cnt,
                                             float* __restrict__ gam, float* __restrict__ bet) {
    int blk = blockIdx.x, tid = threadIdx.x;
    if (blk < 4) {
        int d = blk * 256 + tid;
        float s = 0.f, ss = 0.f;
        for (int g = 0; g < BC; ++g) {
            s += part[g * 2048 + d];
            ss += part[g * 2048 + 1024 + d];
        }
        const float invN = 1.f / 2304.f;
        float m = s * invN;
        float v = ss * invN - m * m;
        mu[d] = m;
        istd[d] = rsqrtf(v + 1e-5f);
        return;
    }
    int o = (blk - 4) * 4 + (tid >> 6);
    int lane = tid & 63;
    int i = o >> 8, c = o & 255;
    {
        const float4* r = (const float4*)(repr + (size_t)i * D);
        const float4* w = (const float4*)(W1T + (size_t)c * D);
        float acc = 0.f;
#pragma unroll
        for (int k = 0; k < 4; ++k) {
            float4 rv = r[k * 64 + lane];
            float4 wv = w[k * 64 + lane];
            acc = fmaf(rv.x, wv.x, acc);
            acc = fmaf(rv.y, wv.y, acc);
            acc = fmaf(rv.z, wv.z, acc);
            acc = fmaf(rv.w, wv.w, acc);
        }
        for (int off = 32; off; off >>= 1) acc += __shfl_xor(acc, off);
        if (lane == 0) {
            float b = (c < 128) ? bg1[c] : bb1[c - 128];
            float hv = fmaxf(acc + b, 0.f);
            // agent-scope store: visible across XCDs at the device coherence point
            __hip_atomic_store(&hid[i * 256 + c], hv, __ATOMIC_RELAXED, __HIP_MEMORY_SCOPE_AGENT);
        }
    }
    __shared__ int sOld;
    __syncthreads();               // all 4 waves' hid stores issued & completed
    if (tid == 0) {
        __threadfence();           // release: hid stores ordered before the count
        sOld = __hip_atomic_fetch_add(&cnt[i], 1, __ATOMIC_ACQ_REL, __HIP_MEMORY_SCOPE_AGENT);
    }
    __syncthreads();
    if (sOld != 63) return;
    // ---- epilogue: this is the last hidden block of image i -> compute gam/bet ----
    __shared__ float h[256];
    h[tid] = __hip_atomic_load(&hid[i * 256 + tid], __ATOMIC_RELAXED, __HIP_MEMORY_SCOPE_AGENT);
    __syncthreads();
    float4 g4 = ((const float4*)bg2)[tid];
    float4 bv = ((const float4*)bb2)[tid];
#pragma unroll 4
    for (int hh = 0; hh < H; ++hh) {
        float hg = h[hh], hb = h[128 + hh];
        float4 wg = ((const float4*)(Wg2 + (size_t)hh * D))[tid];
        float4 wb = ((const float4*)(Wb2 + (size_t)hh * D))[tid];
        g4.x = fmaf(hg, wg.x, g4.x); g4.y = fmaf(hg, wg.y, g4.y);
        g4.z = fmaf(hg, wg.z, g4.z); g4.w = fmaf(hg, wg.w, g4.w);
        bv.x = fmaf(hb, wb.x, bv.x); bv.y = fmaf(hb, wb.y, bv.y);
        bv.z = fmaf(hb, wb.z, bv.z); bv.w = fmaf(hb, wb.w, bv.w);
    }
    float4 go = {1.f + g4.x, 1.f + g4.y, 1.f + g4.z, 1.f + g4.w};
    ((float4*)(gam + (size_t)i * D))[tid] = go;
    ((float4*)(bet + (size_t)i * D))[tid] = bv;
}

// ---------------- Kernel C: main gated-softmax + dot (R5 verbatim) ----------------
// grid (b=64, ig=8) x 512; thread owns adjacent channel pair (2tid, 2tid+1)
__global__ __launch_bounds__(512) void k_main(const float* __restrict__ cap,
                                              const float* __restrict__ mu,
                                              const float* __restrict__ istd,
                                              const float* __restrict__ gam,
                                              const float* __restrict__ bet,
                                              const float* __restrict__ ivec,
                                              float* __restrict__ out) {
    int b = blockIdx.x, ig = blockIdx.y, tid = threadIdx.x;
    const float2* base = (const float2*)(cap + (size_t)b * TCAP * D);
    float2 mu2 = ((const float2*)mu)[tid];
    float2 is2 = ((const float2*)istd)[tid];
    const float A = 14.4269504089f;     // 10 * log2(e)
    const float INV = 0.0693147180560f; // ln(2) / 10

    float a0[8], a1[8], c0[8], c1[8];
    float sw0[8], sw1[8], sxa0[8], sxa1[8];
#pragma unroll
    for (int k = 0; k < 8; ++k) {
        int i = ig * 8 + k;
        float2 g = ((const float2*)(gam + (size_t)i * D))[tid];
        float2 be = ((const float2*)(bet + (size_t)i * D))[tid];
        a0[k] = A * g.x;
        a1[k] = A * g.y;
        c0[k] = A * (be.x - 6.f);
        c1[k] = A * (be.y - 6.f);
        sw0[k] = 0.f; sw1[k] = 0.f; sxa0[k] = 0.f; sxa1[k] = 0.f;
    }
#pragma unroll 4
    for (int t = 0; t < TIMG; ++t) {
        float2 cp = base[t * 512 + tid];
        float x0 = (cp.x - mu2.x) * is2.x;
        float x1 = (cp.y - mu2.y) * is2.y;
#pragma unroll
        for (int k = 0; k < 8; ++k) {
            float arg0 = fmaf(a0[k], x0, c0[k]);
            float e0 = __builtin_amdgcn_exp2f(arg0);
            sw0[k] += e0;
            sxa0[k] = fmaf(e0, arg0, sxa0[k]);
            float arg1 = fmaf(a1[k], x1, c1[k]);
            float e1 = __builtin_amdgcn_exp2f(arg1);
            sw1[k] += e1;
            sxa1[k] = fmaf(e1, arg1, sxa1[k]);
        }
    }
    __shared__ float redS[8][8], redD[8][8];
    int wave = tid >> 6;
#pragma unroll
    for (int k = 0; k < 8; ++k) {
        int i = ig * 8 + k;
        float2 iv = ((const float2*)(ivec + (size_t)i * D))[tid];
        // tv = INV * (sxa/sw) + 6   (since txt = arg*INV + 6)
        float tv0 = fmaf(INV, sxa0[k] / sw0[k], 6.f);
        float tv1 = fmaf(INV, sxa1[k] / sw1[k], 6.f);
        float ss = tv0 * tv0 + tv1 * tv1;
        float sd = iv.x * tv0 + iv.y * tv1;
        for (int off = 32; off; off >>= 1) {
            ss += __shfl_xor(ss, off);
            sd += __shfl_xor(sd, off);
        }
        if ((tid & 63) == 0) { redS[k][wave] = ss; redD[k][wave] = sd; }
    }
    __syncthreads();
    if (tid < 64) {
        int k = tid >> 3, w = tid & 7;
        float s = redS[k][w], d = redD[k][w];
#pragma unroll
        for (int off = 1; off < 8; off <<= 1) {
            s += __shfl_xor(s, off);
            d += __shfl_xor(d, off);
        }
        if (w == 0) {
            int i = ig * 8 + k;
            out[i * BC + b] = d * rsqrtf(s);
        }
    }
}

extern "C" void kernel_launch(void* const* d_in, const int* in_sizes, int n_in,
                              void* d_out, int out_size, void* d_ws, size_t ws_size,
                              hipStream_t stream) {
    const float* img = (const float*)d_in[0];
    const float* cap = (const float*)d_in[1];
    // d_in[2] = lens (unused by the reference)
    const float* Wg1 = (const float*)d_in[3];
    const float* bg1 = (const float*)d_in[4];
    const float* Wg2 = (const float*)d_in[5];
    const float* bg2 = (const float*)d_in[6];
    const float* Wb1 = (const float*)d_in[7];
    const float* bb1 = (const float*)d_in[8];
    const float* Wb2 = (const float*)d_in[9];
    const float* bb2 = (const float*)d_in[10];

    float* ws = (float*)d_ws;
    float* repr = ws;                // 65536
    float* ivec = ws + 65536;        // 65536
    float* gam  = ws + 131072;       // 65536
    float* bet  = ws + 196608;       // 65536
    float* mu   = ws + 262144;       // 1024
    float* istd = ws + 263168;       // 1024
    float* part = ws + 264192;       // 131072
    float* W1T  = ws + 395264;       // 262144
    float* hid  = ws + 657408;       // 16384
    int*   cnt  = (int*)(ws + 673792); // 64 ints
    float* out = (float*)d_out;

    k_pre<<<dim3(193), dim3(1024), 0, stream>>>(img, cap, Wg1, Wb1, repr, ivec, part, W1T, cnt);
    k_mid<<<dim3(4100), dim3(256), 0, stream>>>(part, repr, W1T, bg1, bb1,
                                                Wg2, bg2, Wb2, bb2,
                                                mu, istd, hid, cnt, gam, bet);
    k_main<<<dim3(BC, 8), dim3(512), 0, stream>>>(cap, mu, istd, gam, bet, ivec, out);
}

// Round 13
// 50.802 us; speedup vs baseline: 4.6400x; 4.6400x over previous
//
#include <hip/hip_runtime.h>
#include <hip/hip_bf16.h>

// Sizes (fixed by the reference)
#define BI 64
#define BC 64
#define TCAP 64
#define D 1024
#define H 128
#define TIMG 36

// ---------------- Kernel A: img stats | cap partial stats | W1 transpose ----------------
// grid 192 x 1024:  blk<64: img   64<=blk<128: capstat   128<=blk: w1t
__global__ __launch_bounds__(1024) void k_pre(const float* __restrict__ img,
                                              const float* __restrict__ cap,
                                              const float* __restrict__ Wg1,
                                              const float* __restrict__ Wb1,
                                              float* __restrict__ repr,
                                              float* __restrict__ ivec,
                                              float* __restrict__ part,
                                              float* __restrict__ W1T) {
    int blk = blockIdx.x, tid = threadIdx.x;
    int tg = tid >> 8, dq = tid & 255;      // t-group, float4 channel slot
    __shared__ float4 redA[1024];
    __shared__ float4 redB[1024];
    if (blk < 64) {
        // ---- img_repr mean + l2-normalized img_vec ----
        int i = blk;
        const float4* base = (const float4*)(img + (size_t)i * TIMG * D);
        float4 s = {0.f, 0.f, 0.f, 0.f};
#pragma unroll
        for (int t = 0; t < 9; ++t) {
            float4 v = base[(tg * 9 + t) * 256 + dq];
            s.x += v.x; s.y += v.y; s.z += v.z; s.w += v.w;
        }
        redA[tg * 256 + dq] = s;
        __syncthreads();
        float4 m;
        if (tg == 0) {
            float4 a = redA[dq], b = redA[256 + dq], c = redA[512 + dq], d = redA[768 + dq];
            m.x = (a.x + b.x + c.x + d.x) * (1.f / 36.f);
            m.y = (a.y + b.y + c.y + d.y) * (1.f / 36.f);
            m.z = (a.z + b.z + c.z + d.z) * (1.f / 36.f);
            m.w = (a.w + b.w + c.w + d.w) * (1.f / 36.f);
            ((float4*)(repr + (size_t)i * D))[dq] = m;
            float loc = m.x * m.x + m.y * m.y + m.z * m.z + m.w * m.w;
            for (int off = 32; off; off >>= 1) loc += __shfl_xor(loc, off);
            if ((tid & 63) == 0) redB[dq >> 6].x = loc;   // waves 0..3 of tg0
        }
        __syncthreads();
        if (tg == 0) {
            float inv = rsqrtf(redB[0].x + redB[1].x + redB[2].x + redB[3].x);
            float4 o = {m.x * inv, m.y * inv, m.z * inv, m.w * inv};
            ((float4*)(ivec + (size_t)i * D))[dq] = o;
        }
    } else if (blk < 128) {
        // ---- per-channel sums over t<36 for one caption b ----
        int b = blk - 64;
        const float4* base = (const float4*)(cap + (size_t)b * TCAP * D);
        float4 s = {0.f, 0.f, 0.f, 0.f}, ss = {0.f, 0.f, 0.f, 0.f};
#pragma unroll
        for (int t = 0; t < 9; ++t) {
            float4 v = base[(tg * 9 + t) * 256 + dq];
            s.x += v.x; s.y += v.y; s.z += v.z; s.w += v.w;
            ss.x = fmaf(v.x, v.x, ss.x); ss.y = fmaf(v.y, v.y, ss.y);
            ss.z = fmaf(v.z, v.z, ss.z); ss.w = fmaf(v.w, v.w, ss.w);
        }
        redA[tg * 256 + dq] = s;
        redB[tg * 256 + dq] = ss;
        __syncthreads();
        if (tg == 0) {
            float4 a = redA[dq], b1 = redA[256 + dq], c = redA[512 + dq], d = redA[768 + dq];
            float4 S = {a.x + b1.x + c.x + d.x, a.y + b1.y + c.y + d.y,
                        a.z + b1.z + c.z + d.z, a.w + b1.w + c.w + d.w};
            float4 e = redB[dq], f = redB[256 + dq], g = redB[512 + dq], h = redB[768 + dq];
            float4 SS = {e.x + f.x + g.x + h.x, e.y + f.y + g.y + h.y,
                         e.z + f.z + g.z + h.z, e.w + f.w + g.w + h.w};
            ((float4*)(part + b * 2048))[dq] = S;
            ((float4*)(part + b * 2048 + 1024))[dq] = SS;
        }
    } else {
        // ---- transpose+concat W1 -> W1T[256][1024] (16 waves: 4 rows each pass) ----
        __shared__ float tile[64][65];
        int idx = blk - 128;
        int bx = idx & 15, by = (idx >> 4) & 1, bz = idx >> 5;
        const float* W = bz ? Wb1 : Wg1;
        int d0 = bx * 64, c0 = by * 64;
        int lane = tid & 63, w = tid >> 6;   // w in [0,16)
#pragma unroll
        for (int k = 0; k < 4; ++k) {
            int dl = k * 16 + w;
            tile[dl][lane] = W[(size_t)(d0 + dl) * H + c0 + lane];
        }
        __syncthreads();
#pragma unroll
        for (int k = 0; k < 4; ++k) {
            int cl = k * 16 + w;
            W1T[(size_t)(bz * 128 + c0 + cl) * D + d0 + lane] = tile[lane][cl];
        }
    }
}

// ---------------- Kernel B: stat finalize | hidden layer ----------------
// grid 4100 x 256: blk<4: mu/istd   else: one wave per (i,c) hidden output
__global__ __launch_bounds__(256) void k_mid(const float* __restrict__ part,
                                             const float* __restrict__ repr,
                                             const float* __restrict__ W1T,
                                             const float* __restrict__ bg1,
                                             const float* __restrict__ bb1,
                                             float* __restrict__ mu,
                                             float* __restrict__ istd,
                                             float* __restrict__ hid) {
    int blk = blockIdx.x, tid = threadIdx.x;
    if (blk < 4) {
        int d = blk * 256 + tid;
        float s = 0.f, ss = 0.f;
        for (int g = 0; g < BC; ++g) {
            s += part[g * 2048 + d];
            ss += part[g * 2048 + 1024 + d];
        }
        const float invN = 1.f / 2304.f;
        float m = s * invN;
        float v = ss * invN - m * m;
        mu[d] = m;
        istd[d] = rsqrtf(v + 1e-5f);
    } else {
        int o = (blk - 4) * 4 + (tid >> 6);
        int lane = tid & 63;
        int i = o >> 8, c = o & 255;
        const float4* r = (const float4*)(repr + (size_t)i * D);
        const float4* w = (const float4*)(W1T + (size_t)c * D);
        float acc = 0.f;
#pragma unroll
        for (int k = 0; k < 4; ++k) {
            float4 rv = r[k * 64 + lane];
            float4 wv = w[k * 64 + lane];
            acc = fmaf(rv.x, wv.x, acc);
            acc = fmaf(rv.y, wv.y, acc);
            acc = fmaf(rv.z, wv.z, acc);
            acc = fmaf(rv.w, wv.w, acc);
        }
        for (int off = 32; off; off >>= 1) acc += __shfl_xor(acc, off);
        if (lane == 0) {
            float b = (c < 128) ? bg1[c] : bb1[c - 128];
            hid[o] = fmaxf(acc + b, 0.f);
        }
    }
}

// ---------------- Kernel C: second MLP layer -> gam, bet ----------------
// grid 128 x 256: i = blk>>1, d2 = (blk&1)*256 + tid  (float2 channel index)
__global__ __launch_bounds__(256) void k_out(const float* __restrict__ hid,
                                             const float* __restrict__ Wg2, const float* __restrict__ bg2,
                                             const float* __restrict__ Wb2, const float* __restrict__ bb2,
                                             float* __restrict__ gam, float* __restrict__ bet) {
    int i = blockIdx.x >> 1;
    int d2 = (blockIdx.x & 1) * 256 + threadIdx.x;
    __shared__ float h[256];
    h[threadIdx.x] = hid[i * 256 + threadIdx.x];
    __syncthreads();
    float2 g = ((const float2*)bg2)[d2];
    float2 bb = ((const float2*)bb2)[d2];
#pragma unroll 4
    for (int hh = 0; hh < H; ++hh) {
        float2 wg = ((const float2*)(Wg2 + (size_t)hh * D))[d2];
        float2 wb = ((const float2*)(Wb2 + (size_t)hh * D))[d2];
        float hg = h[hh], hb = h[128 + hh];
        g.x = fmaf(hg, wg.x, g.x);
        g.y = fmaf(hg, wg.y, g.y);
        bb.x = fmaf(hb, wb.x, bb.x);
        bb.y = fmaf(hb, wb.y, bb.y);
    }
    float2 go = {1.f + g.x, 1.f + g.y};
    ((float2*)(gam + (size_t)i * D))[d2] = go;
    ((float2*)(bet + (size_t)i * D))[d2] = bb;
}

// ---------------- Kernel D: main gated-softmax + dot ----------------
// grid (b=64, ig=16) x 512; thread owns channel pair (2tid, 2tid+1); 4 images/block.
// BatchNorm folded into gate coefficients: arg = a'*x + c', a' = A*g*istd,
// c' = A*(bet-6) - a'*mu  ->  inner loop consumes RAW cap values.
__global__ __launch_bounds__(512) void k_main(const float* __restrict__ cap,
                                              const float* __restrict__ mu,
                                              const float* __restrict__ istd,
                                              const float* __restrict__ gam,
                                              const float* __restrict__ bet,
                                              const float* __restrict__ ivec,
                                              float* __restrict__ out) {
    int b = blockIdx.x, ig = blockIdx.y, tid = threadIdx.x;
    const float2* base = (const float2*)(cap + (size_t)b * TCAP * D);
    float2 mu2 = ((const float2*)mu)[tid];
    float2 is2 = ((const float2*)istd)[tid];
    const float A = 14.4269504089f;     // 10 * log2(e)
    const float INV = 0.0693147180560f; // ln(2) / 10

    float a0[4], a1[4], c0[4], c1[4];
    float sw0[4], sw1[4], sxa0[4], sxa1[4];
#pragma unroll
    for (int k = 0; k < 4; ++k) {
        int i = ig * 4 + k;
        float2 g = ((const float2*)(gam + (size_t)i * D))[tid];
        float2 be = ((const float2*)(bet + (size_t)i * D))[tid];
        a0[k] = A * g.x * is2.x;
        a1[k] = A * g.y * is2.y;
        c0[k] = fmaf(-a0[k], mu2.x, A * (be.x - 6.f));
        c1[k] = fmaf(-a1[k], mu2.y, A * (be.y - 6.f));
        sw0[k] = 0.f; sw1[k] = 0.f; sxa0[k] = 0.f; sxa1[k] = 0.f;
    }
#pragma unroll 4
    for (int t = 0; t < TIMG; ++t) {
        float2 cp = base[t * 512 + tid];
#pragma unroll
        for (int k = 0; k < 4; ++k) {
            float arg0 = fmaf(a0[k], cp.x, c0[k]);
            float e0 = __builtin_amdgcn_exp2f(arg0);
            sw0[k] += e0;
            sxa0[k] = fmaf(e0, arg0, sxa0[k]);
            float arg1 = fmaf(a1[k], cp.y, c1[k]);
            float e1 = __builtin_amdgcn_exp2f(arg1);
            sw1[k] += e1;
            sxa1[k] = fmaf(e1, arg1, sxa1[k]);
        }
    }
    __shared__ float redS[4][8], redD[4][8];
    int wave = tid >> 6;
#pragma unroll
    for (int k = 0; k < 4; ++k) {
        int i = ig * 4 + k;
        float2 iv = ((const float2*)(ivec + (size_t)i * D))[tid];
        // tv = INV * (sxa/sw) + 6   (since txt = arg*INV + 6)
        float tv0 = fmaf(INV, sxa0[k] / sw0[k], 6.f);
        float tv1 = fmaf(INV, sxa1[k] / sw1[k], 6.f);
        float ss = tv0 * tv0 + tv1 * tv1;
        float sd = iv.x * tv0 + iv.y * tv1;
        for (int off = 32; off; off >>= 1) {
            ss += __shfl_xor(ss, off);
            sd += __shfl_xor(sd, off);
        }
        if ((tid & 63) == 0) { redS[k][wave] = ss; redD[k][wave] = sd; }
    }
    __syncthreads();
    if (tid < 32) {
        int k = tid >> 3, w = tid & 7;
        float s = redS[k][w], d = redD[k][w];
#pragma unroll
        for (int off = 1; off < 8; off <<= 1) {
            s += __shfl_xor(s, off);
            d += __shfl_xor(d, off);
        }
        if (w == 0) {
            int i = ig * 4 + k;
            out[i * BC + b] = d * rsqrtf(s);
        }
    }
}

extern "C" void kernel_launch(void* const* d_in, const int* in_sizes, int n_in,
                              void* d_out, int out_size, void* d_ws, size_t ws_size,
                              hipStream_t stream) {
    const float* img = (const float*)d_in[0];
    const float* cap = (const float*)d_in[1];
    // d_in[2] = lens (unused by the reference)
    const float* Wg1 = (const float*)d_in[3];
    const float* bg1 = (const float*)d_in[4];
    const float* Wg2 = (const float*)d_in[5];
    const float* bg2 = (const float*)d_in[6];
    const float* Wb1 = (const float*)d_in[7];
    const float* bb1 = (const float*)d_in[8];
    const float* Wb2 = (const float*)d_in[9];
    const float* bb2 = (const float*)d_in[10];

    float* ws = (float*)d_ws;
    float* repr = ws;                // 65536
    float* ivec = ws + 65536;        // 65536
    float* gam  = ws + 131072;       // 65536
    float* bet  = ws + 196608;       // 65536
    float* mu   = ws + 262144;       // 1024
    float* istd = ws + 263168;       // 1024
    float* part = ws + 264192;       // 131072
    float* W1T  = ws + 395264;       // 262144
    float* hid  = ws + 657408;       // 16384
    float* out = (float*)d_out;

    k_pre<<<dim3(192), dim3(1024), 0, stream>>>(img, cap, Wg1, Wb1, repr, ivec, part, W1T);
    k_mid<<<dim3(4100), dim3(256), 0, stream>>>(part, repr, W1T, bg1, bb1, mu, istd, hid);
    k_out<<<dim3(128), dim3(256), 0, stream>>>(hid, Wg2, bg2, Wb2, bb2, gam, bet);
    k_main<<<dim3(BC, 16), dim3(512), 0, stream>>>(cap, mu, istd, gam, bet, ivec, out);
}